// Round 12
// baseline (2932.260 us; speedup 1.0000x reference)
//
#include <hip/hip_runtime.h>
#include <math.h>

typedef __bf16 bf16_t;
typedef __bf16 bf16x8 __attribute__((ext_vector_type(8)));
typedef float f32x4 __attribute__((ext_vector_type(4)));
typedef int i32x4 __attribute__((ext_vector_type(4)));
typedef unsigned int u32;
typedef unsigned long long u64;

#define HID 2048
#define NBATCH 16
#define SEQLEN 512
#define MTOT (NBATCH * SEQLEN)
#define NBLK 32
#define RTHREADS 256
#define LN_EPS 1e-5f

// ================= GEMM: inp = x @ Wi^T + b  -> d_out (fp32) =================
__global__ __launch_bounds__(256) void gemm_proj(
    const float* __restrict__ X,
    const float* __restrict__ Wi,
    const float* __restrict__ bias,
    float* __restrict__ C,
    int* __restrict__ flags)
{
    __shared__ bf16_t lA[128 * 32];
    __shared__ bf16_t lB[128 * 32];
    const int tid = threadIdx.x;
    if (blockIdx.x == 0 && blockIdx.y == 0) {
        if (tid < NBLK * 4) flags[tid] = 0;   // 128 subflags; re-zero EVERY launch
    }
    const int lane = tid & 63;
    const int wv = tid >> 6;
    const int bn = blockIdx.x * 128;
    const int bm = blockIdx.y * 128;
    const int wr = (wv >> 1) * 64;
    const int wc = (wv & 1) * 64;

    f32x4 zero = {0.f, 0.f, 0.f, 0.f};
    f32x4 acc[4][4];
#pragma unroll
    for (int i = 0; i < 4; ++i)
#pragma unroll
        for (int j = 0; j < 4; ++j) acc[i][j] = zero;

    for (int k0 = 0; k0 < HID; k0 += 32) {
        __syncthreads();
#pragma unroll
        for (int c = 0; c < 2; ++c) {
            const int chunk = c * 256 + tid;      // 0..511
            const int row = chunk >> 2;           // 0..127
            const int kp = (chunk & 3) ^ (row & 3); // XOR-swizzled source chunk
            {
                const float* s = X + (size_t)(bm + row) * HID + k0 + kp * 8;
                float4 a0 = *(const float4*)s;
                float4 a1 = *(const float4*)(s + 4);
                bf16x8 v;
                v[0] = (bf16_t)a0.x; v[1] = (bf16_t)a0.y; v[2] = (bf16_t)a0.z; v[3] = (bf16_t)a0.w;
                v[4] = (bf16_t)a1.x; v[5] = (bf16_t)a1.y; v[6] = (bf16_t)a1.z; v[7] = (bf16_t)a1.w;
                *(bf16x8*)(lA + chunk * 8) = v;
            }
            {
                const float* s = Wi + (size_t)(bn + row) * HID + k0 + kp * 8;
                float4 a0 = *(const float4*)s;
                float4 a1 = *(const float4*)(s + 4);
                bf16x8 v;
                v[0] = (bf16_t)a0.x; v[1] = (bf16_t)a0.y; v[2] = (bf16_t)a0.z; v[3] = (bf16_t)a0.w;
                v[4] = (bf16_t)a1.x; v[5] = (bf16_t)a1.y; v[6] = (bf16_t)a1.z; v[7] = (bf16_t)a1.w;
                *(bf16x8*)(lB + chunk * 8) = v;
            }
        }
        __syncthreads();

        bf16x8 af[4], bfr[4];
#pragma unroll
        for (int i = 0; i < 4; ++i) {
            const int row = wr + i * 16 + (lane & 15);
            const int ck = (lane >> 4) ^ (row & 3);
            af[i] = *(const bf16x8*)(lA + row * 32 + ck * 8);
        }
#pragma unroll
        for (int j = 0; j < 4; ++j) {
            const int row = wc + j * 16 + (lane & 15);
            const int ck = (lane >> 4) ^ (row & 3);
            bfr[j] = *(const bf16x8*)(lB + row * 32 + ck * 8);
        }
#pragma unroll
        for (int i = 0; i < 4; ++i)
#pragma unroll
            for (int j = 0; j < 4; ++j)
                acc[i][j] = __builtin_amdgcn_mfma_f32_16x16x32_bf16(af[i], bfr[j], acc[i][j], 0, 0, 0);
    }

#pragma unroll
    for (int j = 0; j < 4; ++j) {
        const int col = bn + wc + j * 16 + (lane & 15);
        const float bv = bias[col];
#pragma unroll
        for (int i = 0; i < 4; ++i) {
#pragma unroll
            for (int r = 0; r < 4; ++r) {
                const int row = bm + wr + i * 16 + (lane >> 4) * 4 + r;
                C[(size_t)row * HID + col] = acc[i][j][r] + bv;
            }
        }
    }
}

// ================= Persistent recurrent kernel =================
// R7 structure (champion: 32 blocks x 4 waves, wf[64] AGPR-backed) with the
// machinery slimmed to 2 barriers/step and per-wave early publish:
//   P: wave0 polls all 128 subflags (64 x u64), s_barrier releases waves.
//   loads (16 x dwordx4 sc0 sc1) + cin prefetch -> counted vmcnt -> 64 MFMA.
//   B: LDS partials, lgkmcnt(0), s_barrier.
//   tail: reduce/update -> 2 state stores -> PER-WAVE vmcnt(0) drain ->
//         lane0 publishes subflag[blk*4+wv] = t+1 -> io store (off-path).
// Safety: subflag(Q,W)=t+1 is published after wave W's step-t loads completed
// (loads < MFMA < LDS-write < barrier B < tail) and after its step-t state
// stores drained; consumer polls ALL 128 before reading buf(t); step-t+1
// writes (into the buffer read at t) happen after barrier P(t+1) joins all
// waves, each past its poll -> every step-t read precedes any overwrite.
__global__ __launch_bounds__(RTHREADS, 1) void recurrent(
    const float* __restrict__ Wr,
    const float* __restrict__ mask,
    const float* __restrict__ tau,
    float* __restrict__ io,      // d_out: holds inp (read rows t+1) -> states (write row t)
    bf16_t* __restrict__ st0,
    bf16_t* __restrict__ st1,
    int* __restrict__ flags)     // [32 blocks][4 waves]
{
    const int tid = threadIdx.x;
    const int lane = tid & 63;
    const int wv = tid >> 6;          // K-quarter 0..3
    const int colbase = blockIdx.x * 64;

    __shared__ float red[4][16][68];  // [kq][batch][col] pad 68

    // ---- preload masked weights: 64 MFMA B-fragments per wave (AGPR-backed) ----
    bf16x8 wf[64];
    {
        const int kb = wv * 512 + (lane >> 4) * 8;
#pragma unroll
        for (int ct = 0; ct < 4; ++ct) {
            const int gc = colbase + ct * 16 + (lane & 15);
#pragma unroll
            for (int kf = 0; kf < 16; ++kf) {
                const size_t off = (size_t)gc * HID + kb + kf * 32;
                float4 a0 = *(const float4*)(Wr + off);
                float4 a1 = *(const float4*)(Wr + off + 4);
                float4 m0 = *(const float4*)(mask + off);
                float4 m1 = *(const float4*)(mask + off + 4);
                bf16x8 v;
                v[0] = (bf16_t)(a0.x * m0.x); v[1] = (bf16_t)(a0.y * m0.y);
                v[2] = (bf16_t)(a0.z * m0.z); v[3] = (bf16_t)(a0.w * m0.w);
                v[4] = (bf16_t)(a1.x * m1.x); v[5] = (bf16_t)(a1.y * m1.y);
                v[6] = (bf16_t)(a1.z * m1.z); v[7] = (bf16_t)(a1.w * m1.w);
                wf[ct * 16 + kf] = v;
            }
        }
    }

    // update mapping: 256 threads <-> 16 batches x 16 col-groups of 4
    const int row = tid >> 4;          // batch 0..15
    const int cg  = (tid & 15) * 4;    // col offset within block
    const int gcol = colbase + cg;
    float al[4];
#pragma unroll
    for (int j = 0; j < 4; ++j) {
        float tv = tau[gcol + j];
        tv = fminf(fmaxf(tv, 1.0f), 20.0f);
        al[j] = fminf(fmaxf(0.5f / tv, 0.0f), 1.0f);
    }

    float s_old[4] = {0.f, 0.f, 0.f, 0.f};
    union F4 { float4 v; float f[4]; };
    F4 cin; cin.v = *(const float4*)(io + (size_t)row * (SEQLEN * HID) + gcol);

    const int akb = wv * 512 + (lane >> 4) * 8;   // A-frag k offset
    int* const myflag = flags + (int)blockIdx.x * 4 + wv;
    bf16_t* cur = st0;
    bf16_t* nxt = st1;

    // ---- step 0: state zero -> rec = 0; store, per-wave drain, publish ----
    {
        float sn[4]; F4 ov;
#pragma unroll
        for (int j = 0; j < 4; ++j) {
            float z = fminf(fmaxf(cin.f[j], -15.f), 15.f);
            const float e = __expf(2.0f * z);
            const float tg = (e - 1.0f) / (e + 1.0f);
            float s = al[j] * tg;
            s = fminf(fmaxf(s, -1.0f), 1.0f);
            sn[j] = s; ov.f[j] = s;
        }
        union { bf16_t b[2]; u32 u; } p0, p1;
        p0.b[0] = (bf16_t)sn[0]; p0.b[1] = (bf16_t)sn[1];
        p1.b[0] = (bf16_t)sn[2]; p1.b[1] = (bf16_t)sn[3];
        u32* sp = (u32*)(nxt + (size_t)row * HID + gcol);
        __hip_atomic_store(sp,     p0.u, __ATOMIC_RELAXED, __HIP_MEMORY_SCOPE_AGENT);
        __hip_atomic_store(sp + 1, p1.u, __ATOMIC_RELAXED, __HIP_MEMORY_SCOPE_AGENT);
        asm volatile("s_waitcnt vmcnt(0)" ::: "memory");
        __builtin_amdgcn_sched_barrier(0);
        if (lane == 0)
            __hip_atomic_store(myflag, 1, __ATOMIC_RELAXED, __HIP_MEMORY_SCOPE_AGENT);
        *(float4*)(io + (size_t)row * (SEQLEN * HID) + gcol) = ov.v;   // off-path
#pragma unroll
        for (int j = 0; j < 4; ++j) s_old[j] = sn[j];
        cin.v = *(const float4*)(io + (size_t)row * (SEQLEN * HID) + HID + gcol);
        bf16_t* tmp = cur; cur = nxt; nxt = tmp;
    }

    for (int t = 1; t < SEQLEN; ++t) {
        // ---- P: wave0 polls all 128 subflags (u64 pairs), barrier releases ----
        if (wv == 0) {
            u64 v;
            do {
                v = __hip_atomic_load((const u64*)flags + lane,
                                      __ATOMIC_RELAXED, __HIP_MEMORY_SCOPE_AGENT);
            } while (__ballot(((int)(v & 0xffffffffu) < t) | ((int)(v >> 32) < t)) != 0ull);
        }
        __builtin_amdgcn_sched_barrier(0);
        asm volatile("s_barrier" ::: "memory");          // P
        __builtin_amdgcn_sched_barrier(0);

        // ---- device-coherent A-fragment loads (16 x 16B) + cin prefetch ----
        const bf16_t* ab = cur + (size_t)(lane & 15) * HID + akb;
        union uf { i32x4 i; bf16x8 v; } a[16];
        asm volatile("global_load_dwordx4 %0, %1, off sc0 sc1"            : "=v"(a[0].i)  : "v"(ab) : "memory");
        asm volatile("global_load_dwordx4 %0, %1, off offset:64 sc0 sc1"  : "=v"(a[1].i)  : "v"(ab) : "memory");
        asm volatile("global_load_dwordx4 %0, %1, off offset:128 sc0 sc1" : "=v"(a[2].i)  : "v"(ab) : "memory");
        asm volatile("global_load_dwordx4 %0, %1, off offset:192 sc0 sc1" : "=v"(a[3].i)  : "v"(ab) : "memory");
        asm volatile("global_load_dwordx4 %0, %1, off offset:256 sc0 sc1" : "=v"(a[4].i)  : "v"(ab) : "memory");
        asm volatile("global_load_dwordx4 %0, %1, off offset:320 sc0 sc1" : "=v"(a[5].i)  : "v"(ab) : "memory");
        asm volatile("global_load_dwordx4 %0, %1, off offset:384 sc0 sc1" : "=v"(a[6].i)  : "v"(ab) : "memory");
        asm volatile("global_load_dwordx4 %0, %1, off offset:448 sc0 sc1" : "=v"(a[7].i)  : "v"(ab) : "memory");
        asm volatile("global_load_dwordx4 %0, %1, off offset:512 sc0 sc1" : "=v"(a[8].i)  : "v"(ab) : "memory");
        asm volatile("global_load_dwordx4 %0, %1, off offset:576 sc0 sc1" : "=v"(a[9].i)  : "v"(ab) : "memory");
        asm volatile("global_load_dwordx4 %0, %1, off offset:640 sc0 sc1" : "=v"(a[10].i) : "v"(ab) : "memory");
        asm volatile("global_load_dwordx4 %0, %1, off offset:704 sc0 sc1" : "=v"(a[11].i) : "v"(ab) : "memory");
        asm volatile("global_load_dwordx4 %0, %1, off offset:768 sc0 sc1" : "=v"(a[12].i) : "v"(ab) : "memory");
        asm volatile("global_load_dwordx4 %0, %1, off offset:832 sc0 sc1" : "=v"(a[13].i) : "v"(ab) : "memory");
        asm volatile("global_load_dwordx4 %0, %1, off offset:896 sc0 sc1" : "=v"(a[14].i) : "v"(ab) : "memory");
        asm volatile("global_load_dwordx4 %0, %1, off offset:960 sc0 sc1" : "=v"(a[15].i) : "v"(ab) : "memory");
        // prefetch next-step input: lands under the MFMA phase (compiler-tracked)
        const int tn = (t < SEQLEN - 1) ? (t + 1) : t;
        F4 cin_next;
        cin_next.v = *(const float4*)(io + (size_t)row * (SEQLEN * HID) + (size_t)tn * HID + gcol);

        f32x4 acc0 = {0.f,0.f,0.f,0.f}, acc1 = {0.f,0.f,0.f,0.f};
        f32x4 acc2 = {0.f,0.f,0.f,0.f}, acc3 = {0.f,0.f,0.f,0.f};

        asm volatile("s_waitcnt vmcnt(9)" ::: "memory");  // a0..a7 landed
        __builtin_amdgcn_sched_barrier(0);
#define MF(kf) \
        acc0 = __builtin_amdgcn_mfma_f32_16x16x32_bf16(a[kf].v, wf[kf],      acc0, 0, 0, 0); \
        acc1 = __builtin_amdgcn_mfma_f32_16x16x32_bf16(a[kf].v, wf[16 + kf], acc1, 0, 0, 0); \
        acc2 = __builtin_amdgcn_mfma_f32_16x16x32_bf16(a[kf].v, wf[32 + kf], acc2, 0, 0, 0); \
        acc3 = __builtin_amdgcn_mfma_f32_16x16x32_bf16(a[kf].v, wf[48 + kf], acc3, 0, 0, 0);
        MF(0) MF(1) MF(2) MF(3) MF(4) MF(5) MF(6) MF(7)
        asm volatile("s_waitcnt vmcnt(1)" ::: "memory");  // a8..a15 landed (cin may fly)
        __builtin_amdgcn_sched_barrier(0);
        MF(8) MF(9) MF(10) MF(11) MF(12) MF(13) MF(14) MF(15)
#undef MF

        // ---- B: LDS partials, lgkmcnt only ----
        {
            const int r0 = (lane >> 4) * 4;
            const int cA = lane & 15;
#pragma unroll
            for (int r = 0; r < 4; ++r) {
                red[wv][r0 + r][cA]      = acc0[r];
                red[wv][r0 + r][16 + cA] = acc1[r];
                red[wv][r0 + r][32 + cA] = acc2[r];
                red[wv][r0 + r][48 + cA] = acc3[r];
            }
        }
        asm volatile("s_waitcnt lgkmcnt(0)" ::: "memory");
        __builtin_amdgcn_sched_barrier(0);
        asm volatile("s_barrier" ::: "memory");          // B
        __builtin_amdgcn_sched_barrier(0);

        F4 s0, s1, s2, s3;
        s0.v = *(const float4*)&red[0][row][cg];
        s1.v = *(const float4*)&red[1][row][cg];
        s2.v = *(const float4*)&red[2][row][cg];
        s3.v = *(const float4*)&red[3][row][cg];

        float sn[4]; F4 ov;
#pragma unroll
        for (int j = 0; j < 4; ++j) {
            const float rec = s0.f[j] + s1.f[j] + s2.f[j] + s3.f[j];
            float z = cin.f[j] + rec;
            z = fminf(fmaxf(z, -15.f), 15.f);
            const float e = __expf(2.0f * z);
            const float tg = (e - 1.0f) / (e + 1.0f);
            float s = s_old[j] + al[j] * (tg - s_old[j]);
            s = fminf(fmaxf(s, -1.0f), 1.0f);
            sn[j] = s; ov.f[j] = s;
        }

        // ---- state stores -> PER-WAVE drain -> lane0 publish -> io (off-path) ----
        union { bf16_t b[2]; u32 u; } p0, p1;
        p0.b[0] = (bf16_t)sn[0]; p0.b[1] = (bf16_t)sn[1];
        p1.b[0] = (bf16_t)sn[2]; p1.b[1] = (bf16_t)sn[3];
        u32* sp = (u32*)(nxt + (size_t)row * HID + gcol);
        __hip_atomic_store(sp,     p0.u, __ATOMIC_RELAXED, __HIP_MEMORY_SCOPE_AGENT);
        __hip_atomic_store(sp + 1, p1.u, __ATOMIC_RELAXED, __HIP_MEMORY_SCOPE_AGENT);
        if (t != SEQLEN - 1) {
            asm volatile("s_waitcnt vmcnt(0)" ::: "memory");
            __builtin_amdgcn_sched_barrier(0);
            if (lane == 0)
                __hip_atomic_store(myflag, t + 1, __ATOMIC_RELAXED, __HIP_MEMORY_SCOPE_AGENT);
        }
        *(float4*)(io + (size_t)row * (SEQLEN * HID) + (size_t)t * HID + gcol) = ov.v;

#pragma unroll
        for (int j = 0; j < 4; ++j) s_old[j] = sn[j];
        cin = cin_next;
        bf16_t* tmp = cur; cur = nxt; nxt = tmp;
    }
}

// ================= LayerNorm (in-place on d_out) =================
__global__ __launch_bounds__(256) void ln_kernel(
    float* __restrict__ io,
    const float* __restrict__ gamma,
    const float* __restrict__ beta)
{
    const size_t row = blockIdx.x;
    float* p = io + row * HID;
    const int tid = threadIdx.x;
    float4 v0 = *(const float4*)(p + tid * 4);
    float4 v1 = *(const float4*)(p + 1024 + tid * 4);
    float s  = v0.x + v0.y + v0.z + v0.w + v1.x + v1.y + v1.z + v1.w;
    float ss = v0.x * v0.x + v0.y * v0.y + v0.z * v0.z + v0.w * v0.w
             + v1.x * v1.x + v1.y * v1.y + v1.z * v1.z + v1.w * v1.w;
#pragma unroll
    for (int off = 32; off > 0; off >>= 1) {
        s  += __shfl_down(s, off, 64);
        ss += __shfl_down(ss, off, 64);
    }
    __shared__ float rs[4], rss[4];
    if ((tid & 63) == 0) { rs[tid >> 6] = s; rss[tid >> 6] = ss; }
    __syncthreads();
    s  = rs[0] + rs[1] + rs[2] + rs[3];
    ss = rss[0] + rss[1] + rss[2] + rss[3];
    const float mu = s * (1.f / HID);
    const float var = ss * (1.f / HID) - mu * mu;
    const float inv = rsqrtf(var + LN_EPS);
    const int c0 = tid * 4, c1 = 1024 + tid * 4;
    float4 g0 = *(const float4*)(gamma + c0);
    float4 g1 = *(const float4*)(gamma + c1);
    float4 b0 = *(const float4*)(beta + c0);
    float4 b1 = *(const float4*)(beta + c1);
    float4 o0, o1;
    o0.x = (v0.x - mu) * inv * g0.x + b0.x;
    o0.y = (v0.y - mu) * inv * g0.y + b0.y;
    o0.z = (v0.z - mu) * inv * g0.z + b0.z;
    o0.w = (v0.w - mu) * inv * g0.w + b0.w;
    o1.x = (v1.x - mu) * inv * g1.x + b1.x;
    o1.y = (v1.y - mu) * inv * g1.y + b1.y;
    o1.z = (v1.z - mu) * inv * g1.z + b1.z;
    o1.w = (v1.w - mu) * inv * g1.w + b1.w;
    *(float4*)(p + tid * 4) = o0;
    *(float4*)(p + 1024 + tid * 4) = o1;
}

extern "C" void kernel_launch(void* const* d_in, const int* in_sizes, int n_in,
                              void* d_out, int out_size, void* d_ws, size_t ws_size,
                              hipStream_t stream)
{
    const float* x     = (const float*)d_in[0];
    const float* Wi    = (const float*)d_in[1];
    const float* bias  = (const float*)d_in[2];
    const float* Wr    = (const float*)d_in[3];
    const float* mask  = (const float*)d_in[4];
    const float* tau   = (const float*)d_in[5];
    const float* gamma = (const float*)d_in[6];
    const float* beta  = (const float*)d_in[7];
    float* out = (float*)d_out;

    bf16_t* st0 = (bf16_t*)d_ws;
    bf16_t* st1 = st0 + (size_t)NBATCH * HID;
    int* flags  = (int*)(st1 + (size_t)NBATCH * HID);

    // 1) input projection -> d_out rows hold inp[b,t,:] (fp32); also zeroes flags
    gemm_proj<<<dim3(16, 64), 256, 0, stream>>>(x, Wi, bias, out, flags);
    // 2) persistent recurrence: overwrites d_out rows with pre-LN states
    recurrent<<<NBLK, RTHREADS, 0, stream>>>(Wr, mask, tau, out, st0, st1, flags);
    // 3) layernorm in-place
    ln_kernel<<<MTOT, 256, 0, stream>>>(out, gamma, beta);
}

// Round 13
// 2222.952 us; speedup vs baseline: 1.3191x; 1.3191x over previous
//
#include <hip/hip_runtime.h>
#include <math.h>

typedef __bf16 bf16_t;
typedef __bf16 bf16x8 __attribute__((ext_vector_type(8)));
typedef float f32x4 __attribute__((ext_vector_type(4)));
typedef int i32x4 __attribute__((ext_vector_type(4)));
typedef unsigned int u32;

#define HID 2048
#define NBATCH 16
#define SEQLEN 512
#define MTOT (NBATCH * SEQLEN)
#define NBLK 32
#define RTHREADS 256
#define LN_EPS 1e-5f

// ================= GEMM: inp = x @ Wi^T + b  -> d_out (fp32) =================
__global__ __launch_bounds__(256) void gemm_proj(
    const float* __restrict__ X,
    const float* __restrict__ Wi,
    const float* __restrict__ bias,
    float* __restrict__ C,
    int* __restrict__ flags)
{
    __shared__ bf16_t lA[128 * 32];
    __shared__ bf16_t lB[128 * 32];
    const int tid = threadIdx.x;
    if (blockIdx.x == 0 && blockIdx.y == 0) {
        if (tid < NBLK) flags[tid] = 0;   // re-zero EVERY launch (graph replay safety)
    }
    const int lane = tid & 63;
    const int wv = tid >> 6;
    const int bn = blockIdx.x * 128;
    const int bm = blockIdx.y * 128;
    const int wr = (wv >> 1) * 64;
    const int wc = (wv & 1) * 64;

    f32x4 zero = {0.f, 0.f, 0.f, 0.f};
    f32x4 acc[4][4];
#pragma unroll
    for (int i = 0; i < 4; ++i)
#pragma unroll
        for (int j = 0; j < 4; ++j) acc[i][j] = zero;

    for (int k0 = 0; k0 < HID; k0 += 32) {
        __syncthreads();
#pragma unroll
        for (int c = 0; c < 2; ++c) {
            const int chunk = c * 256 + tid;      // 0..511
            const int row = chunk >> 2;           // 0..127
            const int kp = (chunk & 3) ^ (row & 3); // XOR-swizzled source chunk
            {
                const float* s = X + (size_t)(bm + row) * HID + k0 + kp * 8;
                float4 a0 = *(const float4*)s;
                float4 a1 = *(const float4*)(s + 4);
                bf16x8 v;
                v[0] = (bf16_t)a0.x; v[1] = (bf16_t)a0.y; v[2] = (bf16_t)a0.z; v[3] = (bf16_t)a0.w;
                v[4] = (bf16_t)a1.x; v[5] = (bf16_t)a1.y; v[6] = (bf16_t)a1.z; v[7] = (bf16_t)a1.w;
                *(bf16x8*)(lA + chunk * 8) = v;
            }
            {
                const float* s = Wi + (size_t)(bn + row) * HID + k0 + kp * 8;
                float4 a0 = *(const float4*)s;
                float4 a1 = *(const float4*)(s + 4);
                bf16x8 v;
                v[0] = (bf16_t)a0.x; v[1] = (bf16_t)a0.y; v[2] = (bf16_t)a0.z; v[3] = (bf16_t)a0.w;
                v[4] = (bf16_t)a1.x; v[5] = (bf16_t)a1.y; v[6] = (bf16_t)a1.z; v[7] = (bf16_t)a1.w;
                *(bf16x8*)(lB + chunk * 8) = v;
            }
        }
        __syncthreads();

        bf16x8 af[4], bfr[4];
#pragma unroll
        for (int i = 0; i < 4; ++i) {
            const int row = wr + i * 16 + (lane & 15);
            const int ck = (lane >> 4) ^ (row & 3);
            af[i] = *(const bf16x8*)(lA + row * 32 + ck * 8);
        }
#pragma unroll
        for (int j = 0; j < 4; ++j) {
            const int row = wc + j * 16 + (lane & 15);
            const int ck = (lane >> 4) ^ (row & 3);
            bfr[j] = *(const bf16x8*)(lB + row * 32 + ck * 8);
        }
#pragma unroll
        for (int i = 0; i < 4; ++i)
#pragma unroll
            for (int j = 0; j < 4; ++j)
                acc[i][j] = __builtin_amdgcn_mfma_f32_16x16x32_bf16(af[i], bfr[j], acc[i][j], 0, 0, 0);
    }

#pragma unroll
    for (int j = 0; j < 4; ++j) {
        const int col = bn + wc + j * 16 + (lane & 15);
        const float bv = bias[col];
#pragma unroll
        for (int i = 0; i < 4; ++i) {
#pragma unroll
            for (int r = 0; r < 4; ++r) {
                const int row = bm + wr + i * 16 + (lane >> 4) * 4 + r;
                C[(size_t)row * HID + col] = acc[i][j][r] + bv;
            }
        }
    }
}

// ================= Persistent recurrent kernel =================
// 32 blocks x 256 thr (4 waves); block owns 64 output cols; wave = K-quarter.
// Per wave: 64 B-frags (4 col-tiles x 16 K-frags) VGPR/AGPR-resident; per step
// 16 A-frag dwordx4 loads (counted vmcnt split) + 64 MFMA; 4-wave LDS reduce.
// Sync protocol (best measured): publish own flag after loop-top
// __syncthreads (compiler drains vmcnt -> prev stores at L3); wave 0 polls all
// 32 flags (ONE cache line); state moves via packed-u32 relaxed agent-scope
// stores / sc0 sc1 dwordx4 loads. Ping-pong safety: flags>=t implies all
// blocks finished iter t-1 reads, so writing buffer(t)=buffer(t-2) is safe.
__global__ __launch_bounds__(RTHREADS, 1) void recurrent(
    const float* __restrict__ Wr,
    const float* __restrict__ mask,
    const float* __restrict__ tau,
    float* __restrict__ io,      // d_out: holds inp (read rows t+1) -> states (write row t)
    bf16_t* __restrict__ st0,
    bf16_t* __restrict__ st1,
    int* __restrict__ flags)     // [32]
{
    const int tid = threadIdx.x;
    const int lane = tid & 63;
    const int wv = tid >> 6;          // K-quarter 0..3
    const int colbase = blockIdx.x * 64;

    __shared__ float red[4][16][68];  // [kq][batch][col] pad 68

    // ---- preload masked weights: 64 MFMA B-fragments per wave (256 VGPR) ----
    bf16x8 wf[64];
    {
        const int kb = wv * 512 + (lane >> 4) * 8;
#pragma unroll
        for (int ct = 0; ct < 4; ++ct) {
            const int gc = colbase + ct * 16 + (lane & 15);
#pragma unroll
            for (int kf = 0; kf < 16; ++kf) {
                const size_t off = (size_t)gc * HID + kb + kf * 32;
                float4 a0 = *(const float4*)(Wr + off);
                float4 a1 = *(const float4*)(Wr + off + 4);
                float4 m0 = *(const float4*)(mask + off);
                float4 m1 = *(const float4*)(mask + off + 4);
                bf16x8 v;
                v[0] = (bf16_t)(a0.x * m0.x); v[1] = (bf16_t)(a0.y * m0.y);
                v[2] = (bf16_t)(a0.z * m0.z); v[3] = (bf16_t)(a0.w * m0.w);
                v[4] = (bf16_t)(a1.x * m1.x); v[5] = (bf16_t)(a1.y * m1.y);
                v[6] = (bf16_t)(a1.z * m1.z); v[7] = (bf16_t)(a1.w * m1.w);
                wf[ct * 16 + kf] = v;
            }
        }
    }

    // update mapping: 256 threads <-> 16 batches x 16 col-groups of 4
    const int row = tid >> 4;          // batch 0..15
    const int cg  = (tid & 15) * 4;    // col offset within block
    const int gcol = colbase + cg;
    float al[4];
#pragma unroll
    for (int j = 0; j < 4; ++j) {
        float tv = tau[gcol + j];
        tv = fminf(fmaxf(tv, 1.0f), 20.0f);
        al[j] = fminf(fmaxf(0.5f / tv, 0.0f), 1.0f);
    }

    float s_old[4] = {0.f, 0.f, 0.f, 0.f};
    union F4 { float4 v; float f[4]; };
    F4 cin; cin.v = *(const float4*)(io + (size_t)row * (SEQLEN * HID) + gcol);

    const int akb = wv * 512 + (lane >> 4) * 8;   // A-frag k offset
    bf16_t* cur = st0;
    bf16_t* nxt = st1;

    // ---- step 0: state zero -> rec = 0 ----
    {
        float sn[4]; F4 ov;
#pragma unroll
        for (int j = 0; j < 4; ++j) {
            float z = fminf(fmaxf(cin.f[j], -15.f), 15.f);
            const float e = __expf(2.0f * z);
            const float tg = (e - 1.0f) / (e + 1.0f);
            float s = al[j] * tg;
            s = fminf(fmaxf(s, -1.0f), 1.0f);
            sn[j] = s; ov.f[j] = s;
        }
        union { bf16_t b[2]; u32 u; } p0, p1;
        p0.b[0] = (bf16_t)sn[0]; p0.b[1] = (bf16_t)sn[1];
        p1.b[0] = (bf16_t)sn[2]; p1.b[1] = (bf16_t)sn[3];
        u32* sp = (u32*)(nxt + (size_t)row * HID + gcol);
        __hip_atomic_store(sp,     p0.u, __ATOMIC_RELAXED, __HIP_MEMORY_SCOPE_AGENT);
        __hip_atomic_store(sp + 1, p1.u, __ATOMIC_RELAXED, __HIP_MEMORY_SCOPE_AGENT);
        *(float4*)(io + (size_t)row * (SEQLEN * HID) + gcol) = ov.v;
#pragma unroll
        for (int j = 0; j < 4; ++j) s_old[j] = sn[j];
        cin.v = *(const float4*)(io + (size_t)row * (SEQLEN * HID) + HID + gcol);
        bf16_t* tmp = cur; cur = nxt; nxt = tmp;
    }

    for (int t = 1; t < SEQLEN; ++t) {
        // ---- loop-top join: drains vmcnt -> step-(t-1) state stores at L3 ----
        __syncthreads();
        if (tid == 0)
            __hip_atomic_store(flags + (int)blockIdx.x, t,
                               __ATOMIC_RELAXED, __HIP_MEMORY_SCOPE_AGENT);
        if (wv == 0) {
            int v;
            do {
                v = __hip_atomic_load(flags + (lane & 31),
                                      __ATOMIC_RELAXED, __HIP_MEMORY_SCOPE_AGENT);
            } while (__ballot(v < t) != 0ull);
        }
        __syncthreads();   // release other waves once data is globally ready

        // ---- device-coherent A-fragment loads (16 x 16B, counted vmcnt) ----
        const bf16_t* ab = cur + (size_t)(lane & 15) * HID + akb;
        union uf { i32x4 i; bf16x8 v; } a[16];
        asm volatile("global_load_dwordx4 %0, %1, off sc0 sc1"            : "=v"(a[0].i)  : "v"(ab) : "memory");
        asm volatile("global_load_dwordx4 %0, %1, off offset:64 sc0 sc1"  : "=v"(a[1].i)  : "v"(ab) : "memory");
        asm volatile("global_load_dwordx4 %0, %1, off offset:128 sc0 sc1" : "=v"(a[2].i)  : "v"(ab) : "memory");
        asm volatile("global_load_dwordx4 %0, %1, off offset:192 sc0 sc1" : "=v"(a[3].i)  : "v"(ab) : "memory");
        asm volatile("global_load_dwordx4 %0, %1, off offset:256 sc0 sc1" : "=v"(a[4].i)  : "v"(ab) : "memory");
        asm volatile("global_load_dwordx4 %0, %1, off offset:320 sc0 sc1" : "=v"(a[5].i)  : "v"(ab) : "memory");
        asm volatile("global_load_dwordx4 %0, %1, off offset:384 sc0 sc1" : "=v"(a[6].i)  : "v"(ab) : "memory");
        asm volatile("global_load_dwordx4 %0, %1, off offset:448 sc0 sc1" : "=v"(a[7].i)  : "v"(ab) : "memory");
        asm volatile("global_load_dwordx4 %0, %1, off offset:512 sc0 sc1" : "=v"(a[8].i)  : "v"(ab) : "memory");
        asm volatile("global_load_dwordx4 %0, %1, off offset:576 sc0 sc1" : "=v"(a[9].i)  : "v"(ab) : "memory");
        asm volatile("global_load_dwordx4 %0, %1, off offset:640 sc0 sc1" : "=v"(a[10].i) : "v"(ab) : "memory");
        asm volatile("global_load_dwordx4 %0, %1, off offset:704 sc0 sc1" : "=v"(a[11].i) : "v"(ab) : "memory");
        asm volatile("global_load_dwordx4 %0, %1, off offset:768 sc0 sc1" : "=v"(a[12].i) : "v"(ab) : "memory");
        asm volatile("global_load_dwordx4 %0, %1, off offset:832 sc0 sc1" : "=v"(a[13].i) : "v"(ab) : "memory");
        asm volatile("global_load_dwordx4 %0, %1, off offset:896 sc0 sc1" : "=v"(a[14].i) : "v"(ab) : "memory");
        asm volatile("global_load_dwordx4 %0, %1, off offset:960 sc0 sc1" : "=v"(a[15].i) : "v"(ab) : "memory");

        f32x4 acc0 = {0.f,0.f,0.f,0.f}, acc1 = {0.f,0.f,0.f,0.f};
        f32x4 acc2 = {0.f,0.f,0.f,0.f}, acc3 = {0.f,0.f,0.f,0.f};

        asm volatile("s_waitcnt vmcnt(8)" ::: "memory");
        __builtin_amdgcn_sched_barrier(0);
#define MF(kf) \
        acc0 = __builtin_amdgcn_mfma_f32_16x16x32_bf16(a[kf].v, wf[kf],      acc0, 0, 0, 0); \
        acc1 = __builtin_amdgcn_mfma_f32_16x16x32_bf16(a[kf].v, wf[16 + kf], acc1, 0, 0, 0); \
        acc2 = __builtin_amdgcn_mfma_f32_16x16x32_bf16(a[kf].v, wf[32 + kf], acc2, 0, 0, 0); \
        acc3 = __builtin_amdgcn_mfma_f32_16x16x32_bf16(a[kf].v, wf[48 + kf], acc3, 0, 0, 0);
        MF(0) MF(1) MF(2) MF(3) MF(4) MF(5) MF(6) MF(7)
        asm volatile("s_waitcnt vmcnt(0)" ::: "memory");
        __builtin_amdgcn_sched_barrier(0);
        MF(8) MF(9) MF(10) MF(11) MF(12) MF(13) MF(14) MF(15)
#undef MF

        // ---- LDS partials (prev-iter reads finished before loop-top barrier) ----
        {
            const int r0 = (lane >> 4) * 4;
            const int cA = lane & 15;
#pragma unroll
            for (int r = 0; r < 4; ++r) {
                red[wv][r0 + r][cA]      = acc0[r];
                red[wv][r0 + r][16 + cA] = acc1[r];
                red[wv][r0 + r][32 + cA] = acc2[r];
                red[wv][r0 + r][48 + cA] = acc3[r];
            }
        }
        __syncthreads();

        F4 s0, s1, s2, s3;
        s0.v = *(const float4*)&red[0][row][cg];
        s1.v = *(const float4*)&red[1][row][cg];
        s2.v = *(const float4*)&red[2][row][cg];
        s3.v = *(const float4*)&red[3][row][cg];

        float sn[4]; F4 ov;
#pragma unroll
        for (int j = 0; j < 4; ++j) {
            const float rec = s0.f[j] + s1.f[j] + s2.f[j] + s3.f[j];
            float z = cin.f[j] + rec;
            z = fminf(fmaxf(z, -15.f), 15.f);
            const float e = __expf(2.0f * z);
            const float tg = (e - 1.0f) / (e + 1.0f);
            float s = s_old[j] + al[j] * (tg - s_old[j]);
            s = fminf(fmaxf(s, -1.0f), 1.0f);
            sn[j] = s; ov.f[j] = s;
        }

        // ---- packed state stores (agent scope, write-through) ----
        union { bf16_t b[2]; u32 u; } p0, p1;
        p0.b[0] = (bf16_t)sn[0]; p0.b[1] = (bf16_t)sn[1];
        p1.b[0] = (bf16_t)sn[2]; p1.b[1] = (bf16_t)sn[3];
        u32* sp = (u32*)(nxt + (size_t)row * HID + gcol);
        __hip_atomic_store(sp,     p0.u, __ATOMIC_RELAXED, __HIP_MEMORY_SCOPE_AGENT);
        __hip_atomic_store(sp + 1, p1.u, __ATOMIC_RELAXED, __HIP_MEMORY_SCOPE_AGENT);

        // ---- off-critical-path: pre-LN output + next input prefetch ----
        *(float4*)(io + (size_t)row * (SEQLEN * HID) + (size_t)t * HID + gcol) = ov.v;
        const int tn = (t < SEQLEN - 1) ? (t + 1) : t;
        cin.v = *(const float4*)(io + (size_t)row * (SEQLEN * HID) + (size_t)tn * HID + gcol);
#pragma unroll
        for (int j = 0; j < 4; ++j) s_old[j] = sn[j];
        bf16_t* tmp = cur; cur = nxt; nxt = tmp;
    }
}

// ================= LayerNorm (in-place on d_out) =================
__global__ __launch_bounds__(256) void ln_kernel(
    float* __restrict__ io,
    const float* __restrict__ gamma,
    const float* __restrict__ beta)
{
    const size_t row = blockIdx.x;
    float* p = io + row * HID;
    const int tid = threadIdx.x;
    float4 v0 = *(const float4*)(p + tid * 4);
    float4 v1 = *(const float4*)(p + 1024 + tid * 4);
    float s  = v0.x + v0.y + v0.z + v0.w + v1.x + v1.y + v1.z + v1.w;
    float ss = v0.x * v0.x + v0.y * v0.y + v0.z * v0.z + v0.w * v0.w
             + v1.x * v1.x + v1.y * v1.y + v1.z * v1.z + v1.w * v1.w;
#pragma unroll
    for (int off = 32; off > 0; off >>= 1) {
        s  += __shfl_down(s, off, 64);
        ss += __shfl_down(ss, off, 64);
    }
    __shared__ float rs[4], rss[4];
    if ((tid & 63) == 0) { rs[tid >> 6] = s; rss[tid >> 6] = ss; }
    __syncthreads();
    s  = rs[0] + rs[1] + rs[2] + rs[3];
    ss = rss[0] + rss[1] + rss[2] + rss[3];
    const float mu = s * (1.f / HID);
    const float var = ss * (1.f / HID) - mu * mu;
    const float inv = rsqrtf(var + LN_EPS);
    const int c0 = tid * 4, c1 = 1024 + tid * 4;
    float4 g0 = *(const float4*)(gamma + c0);
    float4 g1 = *(const float4*)(gamma + c1);
    float4 b0 = *(const float4*)(beta + c0);
    float4 b1 = *(const float4*)(beta + c1);
    float4 o0, o1;
    o0.x = (v0.x - mu) * inv * g0.x + b0.x;
    o0.y = (v0.y - mu) * inv * g0.y + b0.y;
    o0.z = (v0.z - mu) * inv * g0.z + b0.z;
    o0.w = (v0.w - mu) * inv * g0.w + b0.w;
    o1.x = (v1.x - mu) * inv * g1.x + b1.x;
    o1.y = (v1.y - mu) * inv * g1.y + b1.y;
    o1.z = (v1.z - mu) * inv * g1.z + b1.z;
    o1.w = (v1.w - mu) * inv * g1.w + b1.w;
    *(float4*)(p + tid * 4) = o0;
    *(float4*)(p + 1024 + tid * 4) = o1;
}

extern "C" void kernel_launch(void* const* d_in, const int* in_sizes, int n_in,
                              void* d_out, int out_size, void* d_ws, size_t ws_size,
                              hipStream_t stream)
{
    const float* x     = (const float*)d_in[0];
    const float* Wi    = (const float*)d_in[1];
    const float* bias  = (const float*)d_in[2];
    const float* Wr    = (const float*)d_in[3];
    const float* mask  = (const float*)d_in[4];
    const float* tau   = (const float*)d_in[5];
    const float* gamma = (const float*)d_in[6];
    const float* beta  = (const float*)d_in[7];
    float* out = (float*)d_out;

    bf16_t* st0 = (bf16_t*)d_ws;
    bf16_t* st1 = st0 + (size_t)NBATCH * HID;
    int* flags  = (int*)(st1 + (size_t)NBATCH * HID);

    // 1) input projection -> d_out rows hold inp[b,t,:] (fp32); also zeroes flags
    gemm_proj<<<dim3(16, 64), 256, 0, stream>>>(x, Wi, bias, out, flags);
    // 2) persistent recurrence: overwrites d_out rows with pre-LN states
    recurrent<<<NBLK, RTHREADS, 0, stream>>>(Wr, mask, tau, out, st0, st1, flags);
    // 3) layernorm in-place
    ln_kernel<<<MTOT, 256, 0, stream>>>(out, gamma, beta);
}